// Round 15
// baseline (149.614 us; speedup 1.0000x reference)
//
#include <hip/hip_runtime.h>

#define DIM   1024
#define NQKV  3072
#define SEQ   2048
#define HEADS 16
#define DHEAD 64
#define M_TOT 4096   // batch(2) * seq(2048)

typedef __bf16 bf16;
typedef __bf16 bf16x8 __attribute__((ext_vector_type(8)));
typedef float  f32x4  __attribute__((ext_vector_type(4)));

typedef const __attribute__((address_space(1))) unsigned int gu32;
typedef __attribute__((address_space(3))) unsigned int su32;

static __device__ __forceinline__ unsigned short f2b(float f) {
    bf16 h = (bf16)f;
    return __builtin_bit_cast(unsigned short, h);
}

// ---------------- kernel 1: fused prep (cast x -> bf16 | transpose+scale W) ----------------
// R8: transpose in 64x64 tiles, float4 global reads, uint4 global writes.
#define CAST_BLOCKS (M_TOT * DIM / (256 * 4))
#define TR_NB (NQKV / 64)   // 48
__global__ void prep_kernel(const float* __restrict__ x,
                            unsigned short* __restrict__ xb,
                            const float* __restrict__ W,
                            unsigned short* __restrict__ Wt) {
    __shared__ float tile[64][65];   // [n_local][k_local], padded
    const int id  = blockIdx.x;
    const int tid = threadIdx.x;
    if (id < CAST_BLOCKS) {
        int i = (id * 256 + tid) * 4;
        float4 v = *(const float4*)(x + i);
        ushort4 o;
        o.x = f2b(v.x); o.y = f2b(v.y); o.z = f2b(v.z); o.w = f2b(v.w);
        *(ushort4*)(xb + i) = o;
    } else {
        int t  = id - CAST_BLOCKS;
        int nb = t % TR_NB;
        int kb = t / TR_NB;          // 0..15
        #pragma unroll
        for (int p = 0; p < 4; p++) {
            int kl = p * 16 + (tid >> 4);        // 0..63
            int nl = (tid & 15) * 4;             // 0..60
            float4 v = *(const float4*)&W[(size_t)(kb * 64 + kl) * NQKV + nb * 64 + nl];
            tile[nl + 0][kl] = v.x;
            tile[nl + 1][kl] = v.y;
            tile[nl + 2][kl] = v.z;
            tile[nl + 3][kl] = v.w;
        }
        __syncthreads();
        #pragma unroll
        for (int p = 0; p < 2; p++) {
            int nl = p * 32 + (tid >> 3);        // 0..63
            int k8 = (tid & 7) * 8;              // 0..56
            int n  = nb * 64 + nl;
            float s = (n < 1024) ? 0.18033688f : 1.0f;   // 0.125 * log2(e)
            float4 a = *(const float4*)&tile[nl][k8];
            float4 b = *(const float4*)&tile[nl][k8 + 4];
            ushort4 o0, o1;
            o0.x = f2b(a.x * s); o0.y = f2b(a.y * s); o0.z = f2b(a.z * s); o0.w = f2b(a.w * s);
            o1.x = f2b(b.x * s); o1.y = f2b(b.y * s); o1.z = f2b(b.z * s); o1.w = f2b(b.w * s);
            uint4 pk;
            pk.x = ((unsigned)o0.y << 16) | o0.x;
            pk.y = ((unsigned)o0.w << 16) | o0.z;
            pk.z = ((unsigned)o1.y << 16) | o1.x;
            pk.w = ((unsigned)o1.w << 16) | o1.z;
            *(uint4*)&Wt[(size_t)n * DIM + kb * 64 + k8] = pk;
        }
    }
}

// ---------------- kernel 2: QKV GEMM, 128x128 dbuf + counted vmcnt (R21) ----------------
// R21: the __syncthreads() at each K-step drained vmcnt(0) -> the double
// buffer never decoupled (loads issued one compute-phase earlier were waited
// serially; R15's "dbuf neutral" never tested the pipeline). Now: raw
// two-barrier handshake with COUNTED vmcnt (T4/m218): barrier(b: prior
// readers of buf[nxt] done) -> issue 8 gl_lds -> vmcnt(8) (my step-ki loads
// landed; step-ki+1's 8 still flying) -> barrier(a: everyone's landed) ->
// compute. Loads get a full iteration to land. R14 swizzle kept verbatim.
#define LDC 136
__global__ __launch_bounds__(256) void qkv_gemm_kernel(
    const unsigned short* __restrict__ A,
    const unsigned short* __restrict__ Bt,
    unsigned short* __restrict__ Qw,
    unsigned short* __restrict__ Kw,
    unsigned short* __restrict__ Vtw)
{
    __shared__ __align__(16) unsigned char smem[65536];   // 2 bufs x (As 16K | Bs 16K)
    unsigned short* Cs = (unsigned short*)smem;           // epilogue reuse (34816 B)

    const int tid  = threadIdx.x;
    const int m0   = blockIdx.y * 128;
    const int n0   = blockIdx.x * 128;
    const int w    = tid >> 6;
    const int lane = tid & 63;
    const int l16  = lane & 15;
    const int quad = lane >> 4;
    const int wm   = (w >> 1) * 64;
    const int wn   = (w & 1) * 64;
    const int srow = lane >> 3;                      // 0..7 == staged row & 7
    const int scol = ((lane & 7) ^ srow) * 8;        // pre-swizzled source slot
    const int xa   = l16 & 7;                        // read-side swizzle key

    f32x4 acc[4][4];
    const f32x4 fzero = {0.f, 0.f, 0.f, 0.f};
    for (int i = 0; i < 4; i++)
        for (int j = 0; j < 4; j++) acc[i][j] = fzero;

    const unsigned short* Ag = A  + (size_t)(m0 + w * 32 + srow) * DIM + scol;
    const unsigned short* Bg = Bt + (size_t)(n0 + w * 32 + srow) * DIM + scol;

    // prologue: stage K-step 0 into buf 0
    {
        unsigned short* As0 = (unsigned short*)smem;
        unsigned short* Bs0 = (unsigned short*)(smem + 16384);
        #pragma unroll
        for (int j = 0; j < 4; j++) {
            __builtin_amdgcn_global_load_lds((gu32*)(Ag + (size_t)j * 8 * DIM),
                                             (su32*)&As0[(w * 32 + j * 8) * 64], 16, 0, 0);
            __builtin_amdgcn_global_load_lds((gu32*)(Bg + (size_t)j * 8 * DIM),
                                             (su32*)&Bs0[(w * 32 + j * 8) * 64], 16, 0, 0);
        }
    }

    for (int ki = 0; ki < 16; ki++) {
        const int cur = ki & 1, nxt = cur ^ 1;
        asm volatile("s_barrier" ::: "memory");          // (b) prior readers of buf[nxt] done
        if (ki < 15) {   // stage K-step ki+1 into the other buffer
            const int kt = (ki + 1) * 64;
            unsigned short* Asn = (unsigned short*)(smem + nxt * 32768);
            unsigned short* Bsn = (unsigned short*)(smem + nxt * 32768 + 16384);
            #pragma unroll
            for (int j = 0; j < 4; j++) {
                __builtin_amdgcn_global_load_lds((gu32*)(Ag + kt + (size_t)j * 8 * DIM),
                                                 (su32*)&Asn[(w * 32 + j * 8) * 64], 16, 0, 0);
                __builtin_amdgcn_global_load_lds((gu32*)(Bg + kt + (size_t)j * 8 * DIM),
                                                 (su32*)&Bsn[(w * 32 + j * 8) * 64], 16, 0, 0);
            }
            asm volatile("s_waitcnt vmcnt(8)" ::: "memory");   // my step-ki loads landed
        } else {
            asm volatile("s_waitcnt vmcnt(0)" ::: "memory");
        }
        __builtin_amdgcn_sched_barrier(0);
        asm volatile("s_barrier" ::: "memory");          // (a) everyone's step-ki loads landed

        const unsigned short* As = (const unsigned short*)(smem + cur * 32768);
        const unsigned short* Bs = (const unsigned short*)(smem + cur * 32768 + 16384);
        #pragma unroll
        for (int s = 0; s < 2; s++) {
            const int col = ((s * 4 + quad) ^ xa) * 8;   // swizzled 16B slot
            bf16x8 af[4], bfr[4];
            #pragma unroll
            for (int i = 0; i < 4; i++) {
                af[i]  = *(const bf16x8*)(&As[(wm + i * 16 + l16) * 64 + col]);
                bfr[i] = *(const bf16x8*)(&Bs[(wn + i * 16 + l16) * 64 + col]);
            }
            #pragma unroll
            for (int i = 0; i < 4; i++)
                #pragma unroll
                for (int j = 0; j < 4; j++)
                    acc[i][j] = __builtin_amdgcn_mfma_f32_16x16x32_bf16(af[i], bfr[j], acc[i][j], 0, 0, 0);
        }
    }
    __syncthreads();   // all compute done; staging LDS free for Cs overlay

    const int part = n0 >> 10;
    const int h0   = (n0 & 1023) >> 6;
    const int b    = m0 >> 11;
    const int np0  = m0 & 2047;

    if (part < 2) {
        #pragma unroll
        for (int i = 0; i < 4; i++)
            #pragma unroll
            for (int j = 0; j < 4; j++)
                #pragma unroll
                for (int r = 0; r < 4; r++)
                    Cs[(wm + i * 16 + quad * 4 + r) * LDC + wn + j * 16 + l16] = f2b(acc[i][j][r]);
        __syncthreads();
        unsigned short* dst = (part == 0) ? Qw : Kw;
        #pragma unroll
        for (int pass = 0; pass < 8; pass++) {
            int mi = pass * 16 + (tid >> 4);
            int ci = (tid & 15) * 8;
            uint4 v = *(const uint4*)&Cs[mi * LDC + ci];
            int bh = b * HEADS + h0 + (ci >> 6);
            *(uint4*)&dst[((size_t)bh * SEQ + np0 + mi) * DHEAD + (ci & 63)] = v;
        }
    } else {
        #pragma unroll
        for (int i = 0; i < 4; i++)
            #pragma unroll
            for (int j = 0; j < 4; j++) {
                ushort4 pk;
                pk.x = f2b(acc[i][j][0]); pk.y = f2b(acc[i][j][1]);
                pk.z = f2b(acc[i][j][2]); pk.w = f2b(acc[i][j][3]);
                *(ushort4*)&Cs[(wn + j * 16 + l16) * LDC + wm + i * 16 + quad * 4] = pk;
            }
        __syncthreads();
        #pragma unroll
        for (int pass = 0; pass < 8; pass++) {
            int ci = pass * 16 + (tid >> 4);
            int mi = (tid & 15) * 8;
            uint4 v = *(const uint4*)&Cs[ci * LDC + mi];
            int bh = b * HEADS + h0 + (ci >> 6);
            *(uint4*)&Vtw[((size_t)bh * DHEAD + (ci & 63)) * SEQ + np0 + mi] = v;
        }
    }
}

// ---------------- kernel 3: flash attention + residual ----------------
// R16 geometry (measured 42.2us): 64 queries/wave (4 qh chains), 8-wave
// 512-thread blocks, 256-q tiles, grid 256 = 1 block/CU (cache-correct per
// R19's FETCH-explosion lesson). setprio removed (R20: neutral).
// R21: counted-vmcnt two-barrier handshake replaces the draining
// __syncthreads (which forced vmcnt(0) per tile -> dbuf never decoupled).
// Per tile: barrier(b) -> issue 2 gl_lds(t+1) -> vmcnt(2) -> barrier(a) ->
// compute tile t. Loads get a full iteration to land.
__global__ __launch_bounds__(512, 2) void attn_kernel(
    const unsigned short* __restrict__ Qw,
    const unsigned short* __restrict__ Kw,
    const unsigned short* __restrict__ Vtw,
    const float* __restrict__ x,
    float* __restrict__ out)
{
    __shared__ __align__(16) unsigned char smem[65536];  // loop uses 32KB: 2 bufs x (K 8K | V 8K); epilogue scratch 40KB
    unsigned short* base = (unsigned short*)smem;        // buf b: K at b*8192, V at b*8192+4096 (ushorts)
    float* scratch = (float*)smem;

    const int id  = blockIdx.x;
    const int qt  = id >> 5;                                // 0..7 (256-query tiles)
    const int bh  = ((id & 7) << 2) | ((id >> 3) & 3);      // 4 bh per XCD
    const int tid = threadIdx.x;
    const int w   = tid >> 6, lane = tid & 63;
    const int l16 = lane & 15, quad = lane >> 4;
    const int g   = w & 3;      // q-group: queries g*64 .. g*64+63
    const int p   = w >> 2;     // key-half within each 64-key tile (32 keys)
    const int xq  = l16 & 7;    // read-side swizzle key

    const unsigned short* Qb = Qw + ((size_t)bh * SEQ + qt * 256 + g * 64 + l16) * DHEAD;
    bf16x8 qf[4][2];
    #pragma unroll
    for (int qh = 0; qh < 4; qh++) {
        qf[qh][0] = *(const bf16x8*)(Qb + qh * 16 * DHEAD + quad * 8);
        qf[qh][1] = *(const bf16x8*)(Qb + qh * 16 * DHEAD + 32 + quad * 8);
    }

    bf16x8 ones;
    #pragma unroll
    for (int j = 0; j < 8; j++) ones[j] = (bf16)1.0f;

    f32x4 o[4][4], dsum[4];
    const f32x4 fzero = {0.f, 0.f, 0.f, 0.f};
    #pragma unroll
    for (int qh = 0; qh < 4; qh++) {
        #pragma unroll
        for (int d = 0; d < 4; d++) o[qh][d] = fzero;
        dsum[qh] = fzero;
    }

    const unsigned short* Kg = Kw  + (size_t)bh * SEQ * DHEAD;
    const unsigned short* Vg = Vtw + (size_t)bh * DHEAD * SEQ;

    // --- staging source address setup (per-lane): each wave DMAs 8 phys rows ---
    const int sl   = lane >> 3;                 // 0..7 (== pr & 7)
    const int c16s = (lane & 7) ^ sl;           // pre-swizzled 16B slot in source
    const int pr   = 8 * w + sl;                // physical row this lane stages (0..63)
    const int rlog = ((pr >> 2) & 3) * 8 + ((pr >> 4) & 1) * 4 + (pr & 3) + (pr & 32);
    const size_t koff = (size_t)rlog * DHEAD + c16s * 8;   // ushorts, tile-relative
    const size_t voff = (size_t)pr * SEQ + c16s * 8;       // ushorts, tile-relative

    // prologue: stage tile 0 into buf 0 (1 K + 1 V gl_lds per wave)
    __builtin_amdgcn_global_load_lds((gu32*)(Kg + koff), (su32*)(base + w * 512), 16, 0, 0);
    __builtin_amdgcn_global_load_lds((gu32*)(Vg + voff), (su32*)(base + 4096 + w * 512), 16, 0, 0);

    for (int t = 0; t < 32; t++) {
        const int cur = t & 1, nxt = cur ^ 1;
        asm volatile("s_barrier" ::: "memory");          // (b) prior readers of buf[nxt] done
        if (t + 1 < 32) {   // stage tile t+1 into the other buffer
            const size_t kb = (size_t)((t + 1) * 64) * DHEAD;
            const int kv = (t + 1) * 64;
            __builtin_amdgcn_global_load_lds((gu32*)(Kg + kb + koff),
                                             (su32*)(base + nxt * 8192 + w * 512), 16, 0, 0);
            __builtin_amdgcn_global_load_lds((gu32*)(Vg + voff + kv),
                                             (su32*)(base + nxt * 8192 + 4096 + w * 512), 16, 0, 0);
            asm volatile("s_waitcnt vmcnt(2)" ::: "memory");   // my tile-t loads landed
        } else {
            asm volatile("s_waitcnt vmcnt(0)" ::: "memory");
        }
        __builtin_amdgcn_sched_barrier(0);
        asm volatile("s_barrier" ::: "memory");          // (a) everyone's tile-t loads landed

        const unsigned short* Kb = base + cur * 8192;          // [64][64] perm+swz
        const unsigned short* Vb = base + cur * 8192 + 4096;   // V^T [64][64] swz

        // S^T = K_perm · Q^T : this wave's 32 keys x its 64 queries
        f32x4 sacc[4][2];   // [qh][ki]
        #pragma unroll
        for (int qh = 0; qh < 4; qh++)
            #pragma unroll
            for (int ki = 0; ki < 2; ki++) sacc[qh][ki] = fzero;
        #pragma unroll
        for (int s = 0; s < 2; s++) {
            const int col = ((s * 4 + quad) ^ xq) * 8;   // swizzled 16B slot (d-dim)
            #pragma unroll
            for (int ki = 0; ki < 2; ki++) {
                bf16x8 kf = *(const bf16x8*)(&Kb[(p * 32 + ki * 16 + l16) * 64 + col]);
                #pragma unroll
                for (int qh = 0; qh < 4; qh++)
                    sacc[qh][ki] = __builtin_amdgcn_mfma_f32_16x16x32_bf16(kf, qf[qh][s], sacc[qh][ki], 0, 0, 0);
            }
        }

        // p = exp2(s); C-regs are the PV A-frags (K=32 over this half's keys)
        bf16x8 pf[4];
        #pragma unroll
        for (int qh = 0; qh < 4; qh++)
            #pragma unroll
            for (int ki = 0; ki < 2; ki++)
                #pragma unroll
                for (int r = 0; r < 4; r++)
                    pf[qh][ki * 4 + r] = (bf16)__builtin_amdgcn_exp2f(sacc[qh][ki][r]);

        const int colv = ((p * 4 + quad) ^ xq) * 8;       // swizzled V key-slot
        #pragma unroll
        for (int qh = 0; qh < 4; qh++)
            dsum[qh] = __builtin_amdgcn_mfma_f32_16x16x32_bf16(pf[qh], ones, dsum[qh], 0, 0, 0);
        #pragma unroll
        for (int d = 0; d < 4; d++) {
            bf16x8 vf = *(const bf16x8*)(&Vb[(d * 16 + l16) * 64 + colv]);
            #pragma unroll
            for (int qh = 0; qh < 4; qh++)
                o[qh][d] = __builtin_amdgcn_mfma_f32_16x16x32_bf16(pf[qh], vf, o[qh][d], 0, 0, 0);
        }
    }

    // ---- combine the two key-half partials: 2 passes through 40KB scratch ----
    __syncthreads();   // all waves done with K/V LDS before scratch overlay
    #pragma unroll
    for (int ch = 0; ch < 2; ch++) {
        if (ch) __syncthreads();             // pass-0 readers done before overwrite
        if (p == 1) {
            float* sc = scratch + ((size_t)(g * 64 + lane)) * 40;
            #pragma unroll
            for (int q2 = 0; q2 < 2; q2++) {
                int qh = ch * 2 + q2;
                #pragma unroll
                for (int di = 0; di < 4; di++)
                    *(f32x4*)(sc + q2 * 20 + di * 4) = o[qh][di];
                *(f32x4*)(sc + q2 * 20 + 16) = dsum[qh];
            }
        }
        __syncthreads();
        if (p == 0) {
            float* sc = scratch + ((size_t)(g * 64 + lane)) * 40;
            #pragma unroll
            for (int q2 = 0; q2 < 2; q2++) {
                int qh = ch * 2 + q2;
                #pragma unroll
                for (int di = 0; di < 4; di++)
                    o[qh][di] += *(const f32x4*)(sc + q2 * 20 + di * 4);
                dsum[qh] += *(const f32x4*)(sc + q2 * 20 + 16);
            }
        }
    }

    if (p == 0) {
        const int b = bh >> 4, h = bh & 15;
        #pragma unroll
        for (int qh = 0; qh < 4; qh++) {
            float lr[4];
            #pragma unroll
            for (int r = 0; r < 4; r++) lr[r] = __builtin_amdgcn_rcpf(dsum[qh][r]);
            #pragma unroll
            for (int di = 0; di < 4; di++)
                #pragma unroll
                for (int r = 0; r < 4; r++) {
                    int np  = qt * 256 + g * 64 + qh * 16 + quad * 4 + r;
                    int col = h * 64 + di * 16 + l16;
                    size_t gidx = ((size_t)(b * SEQ + np)) * DIM + col;
                    out[gidx] = o[qh][di][r] * lr[r] + x[gidx];
                }
        }
    }
}

extern "C" void kernel_launch(void* const* d_in, const int* in_sizes, int n_in,
                              void* d_out, int out_size, void* d_ws, size_t ws_size,
                              hipStream_t stream) {
    const float* x  = (const float*)d_in[0];   // [2,2048,1024]
    const float* Wq = (const float*)d_in[1];   // [1024,3072]
    float* out = (float*)d_out;

    unsigned short* xb = (unsigned short*)d_ws;                  // [4096][1024]
    unsigned short* Wt = xb + (size_t)M_TOT * DIM;               // [3072][1024]
    unsigned short* Qw = Wt + (size_t)NQKV * DIM;                // [32][2048][64]
    unsigned short* Kw = Qw + (size_t)32 * SEQ * DHEAD;          // [32][2048][64]
    unsigned short* Vt = Kw + (size_t)32 * SEQ * DHEAD;          // [32][64][2048]

    prep_kernel<<<CAST_BLOCKS + TR_NB * (DIM / 64), 256, 0, stream>>>(x, xb, Wq, Wt);
    qkv_gemm_kernel<<<dim3(NQKV / 128, M_TOT / 128), 256, 0, stream>>>(xb, Wt, Qw, Kw, Vt);
    attn_kernel<<<(SEQ / 256) * 32, 512, 0, stream>>>(Qw, Kw, Vt, x, out);
}

// Round 16
// 144.938 us; speedup vs baseline: 1.0323x; 1.0323x over previous
//
#include <hip/hip_runtime.h>

#define DIM   1024
#define NQKV  3072
#define SEQ   2048
#define HEADS 16
#define DHEAD 64
#define M_TOT 4096   // batch(2) * seq(2048)

typedef __bf16 bf16;
typedef __bf16 bf16x8 __attribute__((ext_vector_type(8)));
typedef float  f32x4  __attribute__((ext_vector_type(4)));

typedef const __attribute__((address_space(1))) unsigned int gu32;
typedef __attribute__((address_space(3))) unsigned int su32;

static __device__ __forceinline__ unsigned short f2b(float f) {
    bf16 h = (bf16)f;
    return __builtin_bit_cast(unsigned short, h);
}

// ---------------- kernel 1: fused prep (cast x -> bf16 | transpose+scale W) ----------------
// R8: transpose in 64x64 tiles, float4 global reads, uint4 global writes.
// R22: cast path widened to 8 floats/thread (2x float4 read, 1 uint4 write) --
// prep moves only 44MB but measured ~20us (~2.2TB/s, 35% of achievable);
// halve cast block count + store instructions.
#define CAST_BLOCKS (M_TOT * DIM / (256 * 8))   // 2048
#define TR_NB (NQKV / 64)   // 48
__global__ __launch_bounds__(256) void prep_kernel(
    const float* __restrict__ x,
    unsigned short* __restrict__ xb,
    const float* __restrict__ W,
    unsigned short* __restrict__ Wt) {
    __shared__ float tile[64][65];   // [n_local][k_local], padded
    const int id  = blockIdx.x;
    const int tid = threadIdx.x;
    if (id < CAST_BLOCKS) {
        int i = (id * 256 + tid) * 8;
        float4 a = *(const float4*)(x + i);
        float4 b = *(const float4*)(x + i + 4);
        ushort4 o0, o1;
        o0.x = f2b(a.x); o0.y = f2b(a.y); o0.z = f2b(a.z); o0.w = f2b(a.w);
        o1.x = f2b(b.x); o1.y = f2b(b.y); o1.z = f2b(b.z); o1.w = f2b(b.w);
        uint4 pk;
        pk.x = ((unsigned)o0.y << 16) | o0.x;
        pk.y = ((unsigned)o0.w << 16) | o0.z;
        pk.z = ((unsigned)o1.y << 16) | o1.x;
        pk.w = ((unsigned)o1.w << 16) | o1.z;
        *(uint4*)(xb + i) = pk;
    } else {
        int t  = id - CAST_BLOCKS;
        int nb = t % TR_NB;
        int kb = t / TR_NB;          // 0..15
        #pragma unroll
        for (int p = 0; p < 4; p++) {
            int kl = p * 16 + (tid >> 4);        // 0..63
            int nl = (tid & 15) * 4;             // 0..60
            float4 v = *(const float4*)&W[(size_t)(kb * 64 + kl) * NQKV + nb * 64 + nl];
            tile[nl + 0][kl] = v.x;
            tile[nl + 1][kl] = v.y;
            tile[nl + 2][kl] = v.z;
            tile[nl + 3][kl] = v.w;
        }
        __syncthreads();
        #pragma unroll
        for (int p = 0; p < 2; p++) {
            int nl = p * 32 + (tid >> 3);        // 0..63
            int k8 = (tid & 7) * 8;              // 0..56
            int n  = nb * 64 + nl;
            float s = (n < 1024) ? 0.18033688f : 1.0f;   // 0.125 * log2(e)
            float4 a = *(const float4*)&tile[nl][k8];
            float4 b = *(const float4*)&tile[nl][k8 + 4];
            ushort4 o0, o1;
            o0.x = f2b(a.x * s); o0.y = f2b(a.y * s); o0.z = f2b(a.z * s); o0.w = f2b(a.w * s);
            o1.x = f2b(b.x * s); o1.y = f2b(b.y * s); o1.z = f2b(b.z * s); o1.w = f2b(b.w * s);
            uint4 pk;
            pk.x = ((unsigned)o0.y << 16) | o0.x;
            pk.y = ((unsigned)o0.w << 16) | o0.z;
            pk.z = ((unsigned)o1.y << 16) | o1.x;
            pk.w = ((unsigned)o1.w << 16) | o1.z;
            *(uint4*)&Wt[(size_t)n * DIM + kb * 64 + k8] = pk;
        }
    }
}

// ---------------- kernel 2: QKV GEMM, 256x128 tile (R18, best-known) ----------------
// R14 XOR swizzle (conflicts ~0) + 256x128 tile. In the 145.4us best config.
#define LDC 136
__global__ __launch_bounds__(256, 2) void qkv_gemm_kernel(
    const unsigned short* __restrict__ A,
    const unsigned short* __restrict__ Bt,
    unsigned short* __restrict__ Qw,
    unsigned short* __restrict__ Kw,
    unsigned short* __restrict__ Vtw)
{
    __shared__ __align__(16) unsigned char smem[49152];   // As [256][64] 32K | Bs [128][64] 16K
    unsigned short* As = (unsigned short*)smem;
    unsigned short* Bs = (unsigned short*)(smem + 32768);
    unsigned short* Cs = (unsigned short*)smem;           // epilogue reuse (34816 B)

    const int tid  = threadIdx.x;
    const int m0   = blockIdx.y * 256;
    const int n0   = blockIdx.x * 128;
    const int w    = tid >> 6;
    const int lane = tid & 63;
    const int l16  = lane & 15;
    const int quad = lane >> 4;
    const int wm   = (w >> 1) * 128;                 // wave output rows (128)
    const int wn   = (w & 1) * 64;                   // wave output cols (64)
    const int srow = lane >> 3;                      // 0..7 == staged row & 7
    const int scol = ((lane & 7) ^ srow) * 8;        // pre-swizzled source slot
    const int xa   = l16 & 7;                        // read-side swizzle key

    f32x4 acc[8][4];
    const f32x4 fzero = {0.f, 0.f, 0.f, 0.f};
    #pragma unroll
    for (int i = 0; i < 8; i++)
        #pragma unroll
        for (int j = 0; j < 4; j++) acc[i][j] = fzero;

    const unsigned short* Ag = A  + (size_t)(m0 + w * 64 + srow) * DIM + scol;   // wave stages A rows w*64..+63
    const unsigned short* Bg = Bt + (size_t)(n0 + w * 32 + srow) * DIM + scol;   // wave stages B rows w*32..+31

    for (int ki = 0; ki < 16; ki++) {
        const int kt = ki * 64;
        if (ki > 0) __syncthreads();   // readers of previous step done
        #pragma unroll
        for (int j = 0; j < 8; j++)
            __builtin_amdgcn_global_load_lds((gu32*)(Ag + kt + (size_t)j * 8 * DIM),
                                             (su32*)&As[(w * 64 + j * 8) * 64], 16, 0, 0);
        #pragma unroll
        for (int j = 0; j < 4; j++)
            __builtin_amdgcn_global_load_lds((gu32*)(Bg + kt + (size_t)j * 8 * DIM),
                                             (su32*)&Bs[(w * 32 + j * 8) * 64], 16, 0, 0);
        __syncthreads();   // staged visible (vmcnt drained by compiler)

        #pragma unroll
        for (int s = 0; s < 2; s++) {
            const int col = ((s * 4 + quad) ^ xa) * 8;   // swizzled 16B slot
            bf16x8 af[8], bfr[4];
            #pragma unroll
            for (int i = 0; i < 8; i++)
                af[i]  = *(const bf16x8*)(&As[(wm + i * 16 + l16) * 64 + col]);
            #pragma unroll
            for (int j = 0; j < 4; j++)
                bfr[j] = *(const bf16x8*)(&Bs[(wn + j * 16 + l16) * 64 + col]);
            #pragma unroll
            for (int i = 0; i < 8; i++)
                #pragma unroll
                for (int j = 0; j < 4; j++)
                    acc[i][j] = __builtin_amdgcn_mfma_f32_16x16x32_bf16(af[i], bfr[j], acc[i][j], 0, 0, 0);
        }
    }
    __syncthreads();   // staging LDS free for Cs overlay

    const int part = n0 >> 10;
    const int h0   = (n0 & 1023) >> 6;

    if (part < 2) {
        unsigned short* dst = (part == 0) ? Qw : Kw;
        #pragma unroll
        for (int half = 0; half < 2; half++) {
            if (half) __syncthreads();
            if ((w >> 1) == half) {
                #pragma unroll
                for (int i = 0; i < 8; i++)
                    #pragma unroll
                    for (int j = 0; j < 4; j++)
                        #pragma unroll
                        for (int r = 0; r < 4; r++)
                            Cs[(i * 16 + quad * 4 + r) * LDC + wn + j * 16 + l16] = f2b(acc[i][j][r]);
            }
            __syncthreads();
            const int mg  = m0 + half * 128;
            const int b   = mg >> 11;
            const int npb = mg & 2047;
            #pragma unroll
            for (int pass = 0; pass < 8; pass++) {
                int mi = pass * 16 + (tid >> 4);
                int ci = (tid & 15) * 8;
                uint4 v = *(const uint4*)&Cs[mi * LDC + ci];
                int bh = b * HEADS + h0 + (ci >> 6);
                *(uint4*)&dst[((size_t)bh * SEQ + npb + mi) * DHEAD + (ci & 63)] = v;
            }
        }
    } else {
        #pragma unroll
        for (int half = 0; half < 2; half++) {
            if (half) __syncthreads();
            if ((w >> 1) == half) {
                #pragma unroll
                for (int i = 0; i < 8; i++)
                    #pragma unroll
                    for (int j = 0; j < 4; j++) {
                        ushort4 pk;
                        pk.x = f2b(acc[i][j][0]); pk.y = f2b(acc[i][j][1]);
                        pk.z = f2b(acc[i][j][2]); pk.w = f2b(acc[i][j][3]);
                        *(ushort4*)&Cs[(wn + j * 16 + l16) * LDC + i * 16 + quad * 4] = pk;
                    }
            }
            __syncthreads();
            const int mg  = m0 + half * 128;
            const int b   = mg >> 11;
            const int npb = mg & 2047;
            #pragma unroll
            for (int pass = 0; pass < 8; pass++) {
                int ci = pass * 16 + (tid >> 4);
                int mi = (tid & 15) * 8;
                uint4 v = *(const uint4*)&Cs[ci * LDC + mi];
                int bh = b * HEADS + h0 + (ci >> 6);
                *(uint4*)&Vtw[((size_t)bh * DHEAD + (ci & 63)) * SEQ + npb + mi] = v;
            }
        }
    }
}

// ---------------- kernel 3: flash attention + residual (R16 verbatim, 42.2us) ----------------
// 64 queries/wave (4 qh chains), 8-wave 512-thread blocks = 4 q-groups x
// 2 key-halves-per-tile; 256-q tiles, grid 256 = 1 block/CU. Block-shared
// gl_lds staging (pre-swizzled + row-permuted source), 2-phase dbuf with
// draining __syncthreads. Catalog ledger on this structure: dbuf-neutral,
// barrier-halving-neutral, zero-barrier-worse (R17), counted-vmcnt-worse
// (R21), setprio-neutral (R20), more-blocks-cache-thrash (R19). This is the
// measured local optimum.
__global__ __launch_bounds__(512, 2) void attn_kernel(
    const unsigned short* __restrict__ Qw,
    const unsigned short* __restrict__ Kw,
    const unsigned short* __restrict__ Vtw,
    const float* __restrict__ x,
    float* __restrict__ out)
{
    __shared__ __align__(16) unsigned char smem[65536];  // loop uses 32KB: 2 bufs x (K 8K | V 8K); epilogue scratch 40KB
    unsigned short* base = (unsigned short*)smem;        // buf b: K at b*8192, V at b*8192+4096 (ushorts)
    float* scratch = (float*)smem;

    const int id  = blockIdx.x;
    const int qt  = id >> 5;                                // 0..7 (256-query tiles)
    const int bh  = ((id & 7) << 2) | ((id >> 3) & 3);      // 4 bh per XCD
    const int tid = threadIdx.x;
    const int w   = tid >> 6, lane = tid & 63;
    const int l16 = lane & 15, quad = lane >> 4;
    const int g   = w & 3;      // q-group: queries g*64 .. g*64+63
    const int p   = w >> 2;     // key-half within each 64-key tile (32 keys)
    const int xq  = l16 & 7;    // read-side swizzle key

    const unsigned short* Qb = Qw + ((size_t)bh * SEQ + qt * 256 + g * 64 + l16) * DHEAD;
    bf16x8 qf[4][2];
    #pragma unroll
    for (int qh = 0; qh < 4; qh++) {
        qf[qh][0] = *(const bf16x8*)(Qb + qh * 16 * DHEAD + quad * 8);
        qf[qh][1] = *(const bf16x8*)(Qb + qh * 16 * DHEAD + 32 + quad * 8);
    }

    bf16x8 ones;
    #pragma unroll
    for (int j = 0; j < 8; j++) ones[j] = (bf16)1.0f;

    f32x4 o[4][4], dsum[4];
    const f32x4 fzero = {0.f, 0.f, 0.f, 0.f};
    #pragma unroll
    for (int qh = 0; qh < 4; qh++) {
        #pragma unroll
        for (int d = 0; d < 4; d++) o[qh][d] = fzero;
        dsum[qh] = fzero;
    }

    const unsigned short* Kg = Kw  + (size_t)bh * SEQ * DHEAD;
    const unsigned short* Vg = Vtw + (size_t)bh * DHEAD * SEQ;

    // --- staging source address setup (per-lane): each wave DMAs 8 phys rows ---
    const int sl   = lane >> 3;                 // 0..7 (== pr & 7)
    const int c16s = (lane & 7) ^ sl;           // pre-swizzled 16B slot in source
    const int pr   = 8 * w + sl;                // physical row this lane stages (0..63)
    const int rlog = ((pr >> 2) & 3) * 8 + ((pr >> 4) & 1) * 4 + (pr & 3) + (pr & 32);
    const size_t koff = (size_t)rlog * DHEAD + c16s * 8;   // ushorts, tile-relative
    const size_t voff = (size_t)pr * SEQ + c16s * 8;       // ushorts, tile-relative

    // prologue: stage tile 0 into buf 0 (1 K + 1 V gl_lds per wave)
    __builtin_amdgcn_global_load_lds((gu32*)(Kg + koff), (su32*)(base + w * 512), 16, 0, 0);
    __builtin_amdgcn_global_load_lds((gu32*)(Vg + voff), (su32*)(base + 4096 + w * 512), 16, 0, 0);
    __syncthreads();   // tile 0 resident

    for (int t = 0; t < 32; t++) {
        const int cur = t & 1, nxt = cur ^ 1;
        if (t + 1 < 32) {   // stage tile t+1 into the other buffer
            const size_t kb = (size_t)((t + 1) * 64) * DHEAD;
            const int kv = (t + 1) * 64;
            __builtin_amdgcn_global_load_lds((gu32*)(Kg + kb + koff),
                                             (su32*)(base + nxt * 8192 + w * 512), 16, 0, 0);
            __builtin_amdgcn_global_load_lds((gu32*)(Vg + voff + kv),
                                             (su32*)(base + nxt * 8192 + 4096 + w * 512), 16, 0, 0);
        }

        const unsigned short* Kb = base + cur * 8192;          // [64][64] perm+swz
        const unsigned short* Vb = base + cur * 8192 + 4096;   // V^T [64][64] swz

        // S^T = K_perm · Q^T : this wave's 32 keys x its 64 queries
        f32x4 sacc[4][2];   // [qh][ki]
        #pragma unroll
        for (int qh = 0; qh < 4; qh++)
            #pragma unroll
            for (int ki = 0; ki < 2; ki++) sacc[qh][ki] = fzero;
        #pragma unroll
        for (int s = 0; s < 2; s++) {
            const int col = ((s * 4 + quad) ^ xq) * 8;   // swizzled 16B slot (d-dim)
            #pragma unroll
            for (int ki = 0; ki < 2; ki++) {
                bf16x8 kf = *(const bf16x8*)(&Kb[(p * 32 + ki * 16 + l16) * 64 + col]);
                #pragma unroll
                for (int qh = 0; qh < 4; qh++)
                    sacc[qh][ki] = __builtin_amdgcn_mfma_f32_16x16x32_bf16(kf, qf[qh][s], sacc[qh][ki], 0, 0, 0);
            }
        }

        // p = exp2(s); C-regs are the PV A-frags (K=32 over this half's keys)
        bf16x8 pf[4];
        #pragma unroll
        for (int qh = 0; qh < 4; qh++)
            #pragma unroll
            for (int ki = 0; ki < 2; ki++)
                #pragma unroll
                for (int r = 0; r < 4; r++)
                    pf[qh][ki * 4 + r] = (bf16)__builtin_amdgcn_exp2f(sacc[qh][ki][r]);

        const int colv = ((p * 4 + quad) ^ xq) * 8;       // swizzled V key-slot
        #pragma unroll
        for (int qh = 0; qh < 4; qh++)
            dsum[qh] = __builtin_amdgcn_mfma_f32_16x16x32_bf16(pf[qh], ones, dsum[qh], 0, 0, 0);
        #pragma unroll
        for (int d = 0; d < 4; d++) {
            bf16x8 vf = *(const bf16x8*)(&Vb[(d * 16 + l16) * 64 + colv]);
            #pragma unroll
            for (int qh = 0; qh < 4; qh++)
                o[qh][d] = __builtin_amdgcn_mfma_f32_16x16x32_bf16(pf[qh], vf, o[qh][d], 0, 0, 0);
        }
        __syncthreads();   // drains vmcnt: tile t+1 resident; readers of cur done
    }

    // ---- combine the two key-half partials: 2 passes through 40KB scratch ----
    #pragma unroll
    for (int ch = 0; ch < 2; ch++) {
        if (ch) __syncthreads();             // pass-0 readers done before overwrite
        if (p == 1) {
            float* sc = scratch + ((size_t)(g * 64 + lane)) * 40;
            #pragma unroll
            for (int q2 = 0; q2 < 2; q2++) {
                int qh = ch * 2 + q2;
                #pragma unroll
                for (int di = 0; di < 4; di++)
                    *(f32x4*)(sc + q2 * 20 + di * 4) = o[qh][di];
                *(f32x4*)(sc + q2 * 20 + 16) = dsum[qh];
            }
        }
        __syncthreads();
        if (p == 0) {
            float* sc = scratch + ((size_t)(g * 64 + lane)) * 40;
            #pragma unroll
            for (int q2 = 0; q2 < 2; q2++) {
                int qh = ch * 2 + q2;
                #pragma unroll
                for (int di = 0; di < 4; di++)
                    o[qh][di] += *(const f32x4*)(sc + q2 * 20 + di * 4);
                dsum[qh] += *(const f32x4*)(sc + q2 * 20 + 16);
            }
        }
    }

    if (p == 0) {
        const int b = bh >> 4, h = bh & 15;
        #pragma unroll
        for (int qh = 0; qh < 4; qh++) {
            float lr[4];
            #pragma unroll
            for (int r = 0; r < 4; r++) lr[r] = __builtin_amdgcn_rcpf(dsum[qh][r]);
            #pragma unroll
            for (int di = 0; di < 4; di++)
                #pragma unroll
                for (int r = 0; r < 4; r++) {
                    int np  = qt * 256 + g * 64 + qh * 16 + quad * 4 + r;
                    int col = h * 64 + di * 16 + l16;
                    size_t gidx = ((size_t)(b * SEQ + np)) * DIM + col;
                    out[gidx] = o[qh][di][r] * lr[r] + x[gidx];
                }
        }
    }
}

extern "C" void kernel_launch(void* const* d_in, const int* in_sizes, int n_in,
                              void* d_out, int out_size, void* d_ws, size_t ws_size,
                              hipStream_t stream) {
    const float* x  = (const float*)d_in[0];   // [2,2048,1024]
    const float* Wq = (const float*)d_in[1];   // [1024,3072]
    float* out = (float*)d_out;

    unsigned short* xb = (unsigned short*)d_ws;                  // [4096][1024]
    unsigned short* Wt = xb + (size_t)M_TOT * DIM;               // [3072][1024]
    unsigned short* Qw = Wt + (size_t)NQKV * DIM;                // [32][2048][64]
    unsigned short* Kw = Qw + (size_t)32 * SEQ * DHEAD;          // [32][2048][64]
    unsigned short* Vt = Kw + (size_t)32 * SEQ * DHEAD;          // [32][64][2048]

    prep_kernel<<<CAST_BLOCKS + TR_NB * (DIM / 64), 256, 0, stream>>>(x, xb, Wq, Wt);
    qkv_gemm_kernel<<<dim3(NQKV / 128, M_TOT / 256), 256, 0, stream>>>(xb, Wt, Qw, Kw, Vt);
    attn_kernel<<<(SEQ / 256) * 32, 512, 0, stream>>>(Qw, Kw, Vt, x, out);
}

// Round 17
// 142.991 us; speedup vs baseline: 1.0463x; 1.0136x over previous
//
#include <hip/hip_runtime.h>

#define DIM   1024
#define NQKV  3072
#define SEQ   2048
#define HEADS 16
#define DHEAD 64
#define M_TOT 4096   // batch(2) * seq(2048)

typedef __bf16 bf16;
typedef __bf16 bf16x8 __attribute__((ext_vector_type(8)));
typedef float  f32x4  __attribute__((ext_vector_type(4)));

typedef const __attribute__((address_space(1))) unsigned int gu32;
typedef __attribute__((address_space(3))) unsigned int su32;

static __device__ __forceinline__ unsigned short f2b(float f) {
    bf16 h = (bf16)f;
    return __builtin_bit_cast(unsigned short, h);
}

// ---------------- kernel 1: fused prep (cast x -> bf16 | transpose+scale W) ----------------
// R8: transpose in 64x64 tiles, float4 global reads, uint4 global writes.
// R22: cast path widened to 8 floats/thread (best: 144.9us total).
#define CAST_BLOCKS (M_TOT * DIM / (256 * 8))   // 2048
#define TR_NB (NQKV / 64)   // 48
__global__ __launch_bounds__(256) void prep_kernel(
    const float* __restrict__ x,
    unsigned short* __restrict__ xb,
    const float* __restrict__ W,
    unsigned short* __restrict__ Wt) {
    __shared__ float tile[64][65];   // [n_local][k_local], padded
    const int id  = blockIdx.x;
    const int tid = threadIdx.x;
    if (id < CAST_BLOCKS) {
        int i = (id * 256 + tid) * 8;
        float4 a = *(const float4*)(x + i);
        float4 b = *(const float4*)(x + i + 4);
        ushort4 o0, o1;
        o0.x = f2b(a.x); o0.y = f2b(a.y); o0.z = f2b(a.z); o0.w = f2b(a.w);
        o1.x = f2b(b.x); o1.y = f2b(b.y); o1.z = f2b(b.z); o1.w = f2b(b.w);
        uint4 pk;
        pk.x = ((unsigned)o0.y << 16) | o0.x;
        pk.y = ((unsigned)o0.w << 16) | o0.z;
        pk.z = ((unsigned)o1.y << 16) | o1.x;
        pk.w = ((unsigned)o1.w << 16) | o1.z;
        *(uint4*)(xb + i) = pk;
    } else {
        int t  = id - CAST_BLOCKS;
        int nb = t % TR_NB;
        int kb = t / TR_NB;          // 0..15
        #pragma unroll
        for (int p = 0; p < 4; p++) {
            int kl = p * 16 + (tid >> 4);        // 0..63
            int nl = (tid & 15) * 4;             // 0..60
            float4 v = *(const float4*)&W[(size_t)(kb * 64 + kl) * NQKV + nb * 64 + nl];
            tile[nl + 0][kl] = v.x;
            tile[nl + 1][kl] = v.y;
            tile[nl + 2][kl] = v.z;
            tile[nl + 3][kl] = v.w;
        }
        __syncthreads();
        #pragma unroll
        for (int p = 0; p < 2; p++) {
            int nl = p * 32 + (tid >> 3);        // 0..63
            int k8 = (tid & 7) * 8;              // 0..56
            int n  = nb * 64 + nl;
            float s = (n < 1024) ? 0.18033688f : 1.0f;   // 0.125 * log2(e)
            float4 a = *(const float4*)&tile[nl][k8];
            float4 b = *(const float4*)&tile[nl][k8 + 4];
            ushort4 o0, o1;
            o0.x = f2b(a.x * s); o0.y = f2b(a.y * s); o0.z = f2b(a.z * s); o0.w = f2b(a.w * s);
            o1.x = f2b(b.x * s); o1.y = f2b(b.y * s); o1.z = f2b(b.z * s); o1.w = f2b(b.w * s);
            uint4 pk;
            pk.x = ((unsigned)o0.y << 16) | o0.x;
            pk.y = ((unsigned)o0.w << 16) | o0.z;
            pk.z = ((unsigned)o1.y << 16) | o1.x;
            pk.w = ((unsigned)o1.w << 16) | o1.z;
            *(uint4*)&Wt[(size_t)n * DIM + kb * 64 + k8] = pk;
        }
    }
}

// ---------------- kernel 2: QKV GEMM, 128x128 dbuf + counted vmcnt (R21 gemm) ----------------
// R23: recombination — R21's total regression was entirely attn's (+6.2us);
// decomposition arithmetic put THIS gemm at ~38.5us vs R18's ~40 (within
// noise, but the only positive pipelining signal of the session). Two-barrier
// counted-vmcnt handshake: barrier(b) -> issue 8 gl_lds -> vmcnt(8) ->
// barrier(a) -> compute; loads get a full iteration to land. R14 XOR swizzle
// verbatim (conflicts ~0). Grid 768 (balanced) vs R18's 384 (1.5/CU).
#define LDC 136
__global__ __launch_bounds__(256) void qkv_gemm_kernel(
    const unsigned short* __restrict__ A,
    const unsigned short* __restrict__ Bt,
    unsigned short* __restrict__ Qw,
    unsigned short* __restrict__ Kw,
    unsigned short* __restrict__ Vtw)
{
    __shared__ __align__(16) unsigned char smem[65536];   // 2 bufs x (As 16K | Bs 16K)
    unsigned short* Cs = (unsigned short*)smem;           // epilogue reuse (34816 B)

    const int tid  = threadIdx.x;
    const int m0   = blockIdx.y * 128;
    const int n0   = blockIdx.x * 128;
    const int w    = tid >> 6;
    const int lane = tid & 63;
    const int l16  = lane & 15;
    const int quad = lane >> 4;
    const int wm   = (w >> 1) * 64;
    const int wn   = (w & 1) * 64;
    const int srow = lane >> 3;                      // 0..7 == staged row & 7
    const int scol = ((lane & 7) ^ srow) * 8;        // pre-swizzled source slot
    const int xa   = l16 & 7;                        // read-side swizzle key

    f32x4 acc[4][4];
    const f32x4 fzero = {0.f, 0.f, 0.f, 0.f};
    for (int i = 0; i < 4; i++)
        for (int j = 0; j < 4; j++) acc[i][j] = fzero;

    const unsigned short* Ag = A  + (size_t)(m0 + w * 32 + srow) * DIM + scol;
    const unsigned short* Bg = Bt + (size_t)(n0 + w * 32 + srow) * DIM + scol;

    // prologue: stage K-step 0 into buf 0
    {
        unsigned short* As0 = (unsigned short*)smem;
        unsigned short* Bs0 = (unsigned short*)(smem + 16384);
        #pragma unroll
        for (int j = 0; j < 4; j++) {
            __builtin_amdgcn_global_load_lds((gu32*)(Ag + (size_t)j * 8 * DIM),
                                             (su32*)&As0[(w * 32 + j * 8) * 64], 16, 0, 0);
            __builtin_amdgcn_global_load_lds((gu32*)(Bg + (size_t)j * 8 * DIM),
                                             (su32*)&Bs0[(w * 32 + j * 8) * 64], 16, 0, 0);
        }
    }

    for (int ki = 0; ki < 16; ki++) {
        const int cur = ki & 1, nxt = cur ^ 1;
        asm volatile("s_barrier" ::: "memory");          // (b) prior readers of buf[nxt] done
        if (ki < 15) {   // stage K-step ki+1 into the other buffer
            const int kt = (ki + 1) * 64;
            unsigned short* Asn = (unsigned short*)(smem + nxt * 32768);
            unsigned short* Bsn = (unsigned short*)(smem + nxt * 32768 + 16384);
            #pragma unroll
            for (int j = 0; j < 4; j++) {
                __builtin_amdgcn_global_load_lds((gu32*)(Ag + kt + (size_t)j * 8 * DIM),
                                                 (su32*)&Asn[(w * 32 + j * 8) * 64], 16, 0, 0);
                __builtin_amdgcn_global_load_lds((gu32*)(Bg + kt + (size_t)j * 8 * DIM),
                                                 (su32*)&Bsn[(w * 32 + j * 8) * 64], 16, 0, 0);
            }
            asm volatile("s_waitcnt vmcnt(8)" ::: "memory");   // my step-ki loads landed
        } else {
            asm volatile("s_waitcnt vmcnt(0)" ::: "memory");
        }
        __builtin_amdgcn_sched_barrier(0);
        asm volatile("s_barrier" ::: "memory");          // (a) everyone's step-ki loads landed

        const unsigned short* As = (const unsigned short*)(smem + cur * 32768);
        const unsigned short* Bs = (const unsigned short*)(smem + cur * 32768 + 16384);
        #pragma unroll
        for (int s = 0; s < 2; s++) {
            const int col = ((s * 4 + quad) ^ xa) * 8;   // swizzled 16B slot
            bf16x8 af[4], bfr[4];
            #pragma unroll
            for (int i = 0; i < 4; i++) {
                af[i]  = *(const bf16x8*)(&As[(wm + i * 16 + l16) * 64 + col]);
                bfr[i] = *(const bf16x8*)(&Bs[(wn + i * 16 + l16) * 64 + col]);
            }
            #pragma unroll
            for (int i = 0; i < 4; i++)
                #pragma unroll
                for (int j = 0; j < 4; j++)
                    acc[i][j] = __builtin_amdgcn_mfma_f32_16x16x32_bf16(af[i], bfr[j], acc[i][j], 0, 0, 0);
        }
    }
    __syncthreads();   // all compute done; staging LDS free for Cs overlay

    const int part = n0 >> 10;
    const int h0   = (n0 & 1023) >> 6;
    const int b    = m0 >> 11;
    const int np0  = m0 & 2047;

    if (part < 2) {
        #pragma unroll
        for (int i = 0; i < 4; i++)
            #pragma unroll
            for (int j = 0; j < 4; j++)
                #pragma unroll
                for (int r = 0; r < 4; r++)
                    Cs[(wm + i * 16 + quad * 4 + r) * LDC + wn + j * 16 + l16] = f2b(acc[i][j][r]);
        __syncthreads();
        unsigned short* dst = (part == 0) ? Qw : Kw;
        #pragma unroll
        for (int pass = 0; pass < 8; pass++) {
            int mi = pass * 16 + (tid >> 4);
            int ci = (tid & 15) * 8;
            uint4 v = *(const uint4*)&Cs[mi * LDC + ci];
            int bh = b * HEADS + h0 + (ci >> 6);
            *(uint4*)&dst[((size_t)bh * SEQ + np0 + mi) * DHEAD + (ci & 63)] = v;
        }
    } else {
        #pragma unroll
        for (int i = 0; i < 4; i++)
            #pragma unroll
            for (int j = 0; j < 4; j++) {
                ushort4 pk;
                pk.x = f2b(acc[i][j][0]); pk.y = f2b(acc[i][j][1]);
                pk.z = f2b(acc[i][j][2]); pk.w = f2b(acc[i][j][3]);
                *(ushort4*)&Cs[(wn + j * 16 + l16) * LDC + wm + i * 16 + quad * 4] = pk;
            }
        __syncthreads();
        #pragma unroll
        for (int pass = 0; pass < 8; pass++) {
            int ci = pass * 16 + (tid >> 4);
            int mi = (tid & 15) * 8;
            uint4 v = *(const uint4*)&Cs[ci * LDC + mi];
            int bh = b * HEADS + h0 + (ci >> 6);
            *(uint4*)&Vtw[((size_t)bh * DHEAD + (ci & 63)) * SEQ + np0 + mi] = v;
        }
    }
}

// ---------------- kernel 3: flash attention + residual (R16 verbatim, 42.2us) ----------------
// 64 queries/wave (4 qh chains), 8-wave 512-thread blocks = 4 q-groups x
// 2 key-halves-per-tile; 256-q tiles, grid 256 = 1 block/CU. Block-shared
// gl_lds staging (pre-swizzled + row-permuted source), 2-phase dbuf with
// draining __syncthreads. Ledger: dbuf-neutral, barrier-halving-neutral,
// zero-barrier-worse (R17), counted-vmcnt-worse (R21), setprio-neutral (R20),
// more-blocks-cache-thrash (R19). Measured local optimum.
__global__ __launch_bounds__(512, 2) void attn_kernel(
    const unsigned short* __restrict__ Qw,
    const unsigned short* __restrict__ Kw,
    const unsigned short* __restrict__ Vtw,
    const float* __restrict__ x,
    float* __restrict__ out)
{
    __shared__ __align__(16) unsigned char smem[65536];  // loop uses 32KB: 2 bufs x (K 8K | V 8K); epilogue scratch 40KB
    unsigned short* base = (unsigned short*)smem;        // buf b: K at b*8192, V at b*8192+4096 (ushorts)
    float* scratch = (float*)smem;

    const int id  = blockIdx.x;
    const int qt  = id >> 5;                                // 0..7 (256-query tiles)
    const int bh  = ((id & 7) << 2) | ((id >> 3) & 3);      // 4 bh per XCD
    const int tid = threadIdx.x;
    const int w   = tid >> 6, lane = tid & 63;
    const int l16 = lane & 15, quad = lane >> 4;
    const int g   = w & 3;      // q-group: queries g*64 .. g*64+63
    const int p   = w >> 2;     // key-half within each 64-key tile (32 keys)
    const int xq  = l16 & 7;    // read-side swizzle key

    const unsigned short* Qb = Qw + ((size_t)bh * SEQ + qt * 256 + g * 64 + l16) * DHEAD;
    bf16x8 qf[4][2];
    #pragma unroll
    for (int qh = 0; qh < 4; qh++) {
        qf[qh][0] = *(const bf16x8*)(Qb + qh * 16 * DHEAD + quad * 8);
        qf[qh][1] = *(const bf16x8*)(Qb + qh * 16 * DHEAD + 32 + quad * 8);
    }

    bf16x8 ones;
    #pragma unroll
    for (int j = 0; j < 8; j++) ones[j] = (bf16)1.0f;

    f32x4 o[4][4], dsum[4];
    const f32x4 fzero = {0.f, 0.f, 0.f, 0.f};
    #pragma unroll
    for (int qh = 0; qh < 4; qh++) {
        #pragma unroll
        for (int d = 0; d < 4; d++) o[qh][d] = fzero;
        dsum[qh] = fzero;
    }

    const unsigned short* Kg = Kw  + (size_t)bh * SEQ * DHEAD;
    const unsigned short* Vg = Vtw + (size_t)bh * DHEAD * SEQ;

    // --- staging source address setup (per-lane): each wave DMAs 8 phys rows ---
    const int sl   = lane >> 3;                 // 0..7 (== pr & 7)
    const int c16s = (lane & 7) ^ sl;           // pre-swizzled 16B slot in source
    const int pr   = 8 * w + sl;                // physical row this lane stages (0..63)
    const int rlog = ((pr >> 2) & 3) * 8 + ((pr >> 4) & 1) * 4 + (pr & 3) + (pr & 32);
    const size_t koff = (size_t)rlog * DHEAD + c16s * 8;   // ushorts, tile-relative
    const size_t voff = (size_t)pr * SEQ + c16s * 8;       // ushorts, tile-relative

    // prologue: stage tile 0 into buf 0 (1 K + 1 V gl_lds per wave)
    __builtin_amdgcn_global_load_lds((gu32*)(Kg + koff), (su32*)(base + w * 512), 16, 0, 0);
    __builtin_amdgcn_global_load_lds((gu32*)(Vg + voff), (su32*)(base + 4096 + w * 512), 16, 0, 0);
    __syncthreads();   // tile 0 resident

    for (int t = 0; t < 32; t++) {
        const int cur = t & 1, nxt = cur ^ 1;
        if (t + 1 < 32) {   // stage tile t+1 into the other buffer
            const size_t kb = (size_t)((t + 1) * 64) * DHEAD;
            const int kv = (t + 1) * 64;
            __builtin_amdgcn_global_load_lds((gu32*)(Kg + kb + koff),
                                             (su32*)(base + nxt * 8192 + w * 512), 16, 0, 0);
            __builtin_amdgcn_global_load_lds((gu32*)(Vg + voff + kv),
                                             (su32*)(base + nxt * 8192 + 4096 + w * 512), 16, 0, 0);
        }

        const unsigned short* Kb = base + cur * 8192;          // [64][64] perm+swz
        const unsigned short* Vb = base + cur * 8192 + 4096;   // V^T [64][64] swz

        // S^T = K_perm · Q^T : this wave's 32 keys x its 64 queries
        f32x4 sacc[4][2];   // [qh][ki]
        #pragma unroll
        for (int qh = 0; qh < 4; qh++)
            #pragma unroll
            for (int ki = 0; ki < 2; ki++) sacc[qh][ki] = fzero;
        #pragma unroll
        for (int s = 0; s < 2; s++) {
            const int col = ((s * 4 + quad) ^ xq) * 8;   // swizzled 16B slot (d-dim)
            #pragma unroll
            for (int ki = 0; ki < 2; ki++) {
                bf16x8 kf = *(const bf16x8*)(&Kb[(p * 32 + ki * 16 + l16) * 64 + col]);
                #pragma unroll
                for (int qh = 0; qh < 4; qh++)
                    sacc[qh][ki] = __builtin_amdgcn_mfma_f32_16x16x32_bf16(kf, qf[qh][s], sacc[qh][ki], 0, 0, 0);
            }
        }

        // p = exp2(s); C-regs are the PV A-frags (K=32 over this half's keys)
        bf16x8 pf[4];
        #pragma unroll
        for (int qh = 0; qh < 4; qh++)
            #pragma unroll
            for (int ki = 0; ki < 2; ki++)
                #pragma unroll
                for (int r = 0; r < 4; r++)
                    pf[qh][ki * 4 + r] = (bf16)__builtin_amdgcn_exp2f(sacc[qh][ki][r]);

        const int colv = ((p * 4 + quad) ^ xq) * 8;       // swizzled V key-slot
        #pragma unroll
        for (int qh = 0; qh < 4; qh++)
            dsum[qh] = __builtin_amdgcn_mfma_f32_16x16x32_bf16(pf[qh], ones, dsum[qh], 0, 0, 0);
        #pragma unroll
        for (int d = 0; d < 4; d++) {
            bf16x8 vf = *(const bf16x8*)(&Vb[(d * 16 + l16) * 64 + colv]);
            #pragma unroll
            for (int qh = 0; qh < 4; qh++)
                o[qh][d] = __builtin_amdgcn_mfma_f32_16x16x32_bf16(pf[qh], vf, o[qh][d], 0, 0, 0);
        }
        __syncthreads();   // drains vmcnt: tile t+1 resident; readers of cur done
    }

    // ---- combine the two key-half partials: 2 passes through 40KB scratch ----
    #pragma unroll
    for (int ch = 0; ch < 2; ch++) {
        if (ch) __syncthreads();             // pass-0 readers done before overwrite
        if (p == 1) {
            float* sc = scratch + ((size_t)(g * 64 + lane)) * 40;
            #pragma unroll
            for (int q2 = 0; q2 < 2; q2++) {
                int qh = ch * 2 + q2;
                #pragma unroll
                for (int di = 0; di < 4; di++)
                    *(f32x4*)(sc + q2 * 20 + di * 4) = o[qh][di];
                *(f32x4*)(sc + q2 * 20 + 16) = dsum[qh];
            }
        }
        __syncthreads();
        if (p == 0) {
            float* sc = scratch + ((size_t)(g * 64 + lane)) * 40;
            #pragma unroll
            for (int q2 = 0; q2 < 2; q2++) {
                int qh = ch * 2 + q2;
                #pragma unroll
                for (int di = 0; di < 4; di++)
                    o[qh][di] += *(const f32x4*)(sc + q2 * 20 + di * 4);
                dsum[qh] += *(const f32x4*)(sc + q2 * 20 + 16);
            }
        }
    }

    if (p == 0) {
        const int b = bh >> 4, h = bh & 15;
        #pragma unroll
        for (int qh = 0; qh < 4; qh++) {
            float lr[4];
            #pragma unroll
            for (int r = 0; r < 4; r++) lr[r] = __builtin_amdgcn_rcpf(dsum[qh][r]);
            #pragma unroll
            for (int di = 0; di < 4; di++)
                #pragma unroll
                for (int r = 0; r < 4; r++) {
                    int np  = qt * 256 + g * 64 + qh * 16 + quad * 4 + r;
                    int col = h * 64 + di * 16 + l16;
                    size_t gidx = ((size_t)(b * SEQ + np)) * DIM + col;
                    out[gidx] = o[qh][di][r] * lr[r] + x[gidx];
                }
        }
    }
}

extern "C" void kernel_launch(void* const* d_in, const int* in_sizes, int n_in,
                              void* d_out, int out_size, void* d_ws, size_t ws_size,
                              hipStream_t stream) {
    const float* x  = (const float*)d_in[0];   // [2,2048,1024]
    const float* Wq = (const float*)d_in[1];   // [1024,3072]
    float* out = (float*)d_out;

    unsigned short* xb = (unsigned short*)d_ws;                  // [4096][1024]
    unsigned short* Wt = xb + (size_t)M_TOT * DIM;               // [3072][1024]
    unsigned short* Qw = Wt + (size_t)NQKV * DIM;                // [32][2048][64]
    unsigned short* Kw = Qw + (size_t)32 * SEQ * DHEAD;          // [32][2048][64]
    unsigned short* Vt = Kw + (size_t)32 * SEQ * DHEAD;          // [32][64][2048]

    prep_kernel<<<CAST_BLOCKS + TR_NB * (DIM / 64), 256, 0, stream>>>(x, xb, Wq, Wt);
    qkv_gemm_kernel<<<dim3(NQKV / 128, M_TOT / 128), 256, 0, stream>>>(xb, Wt, Qw, Kw, Vt);
    attn_kernel<<<(SEQ / 256) * 32, 512, 0, stream>>>(Qw, Kw, Vt, x, out);
}